// Round 14
// baseline (27.583 us; speedup 1.0000x reference)
//
#include <hip/hip_runtime.h>
#include <hip/hip_bf16.h>

// Problem constants (from reference)
#define T_LEN 2048
#define D_DIM 64
#define K_CH  8
#define B_SZ  8

// Single-kernel block-local scan: block = (b,k); 1024 threads = 16 waves x
// 64 d-lanes; wave w owns t-segment [w*SEG, (w+1)*SEG), SEG=128.
// No cross-block dependency at all — the T-scan is intra-block via LDS.
#define SEG 128
#define NW (T_LEN / SEG)       // 16 waves

__device__ __forceinline__ float2 cmul(float2 a, float2 b) {
    return make_float2(a.x * b.x - a.y * b.y, a.x * b.y + a.y * b.x);
}
__device__ __forceinline__ float2 cadd(float2 a, float2 b) {
    return make_float2(a.x + b.x, a.y + b.y);
}

__global__ __launch_bounds__(1024) void s4d_block(
    const float* __restrict__ h,
    const float* __restrict__ log_neg_re,
    const float* __restrict__ imag,
    const float* __restrict__ B_proj,
    const float* __restrict__ log_dt,
    float* __restrict__ out)
{
    const int bid = blockIdx.x;
    const int b = bid & 7;           // bid%8 = b -> all of sequence b's
    const int k = bid >> 3;          // blocks land on one XCD (h L2-local)
    const int w = threadIdx.x >> 6;  // wave id = t-segment
    const int d = threadIdx.x & 63;  // lane = d

    // ---- per-k constants (closed form, matches reference) ----
    const float dt = expf(log_dt[0]);
    const float re = -expf(log_neg_re[k]);
    const float im = imag[k];
    const float mag = expf(re * dt);
    const float2 A  = make_float2(mag * cosf(im * dt), mag * sinf(im * dt));
    const float2 A2 = cmul(A, A);
    const float2 A3 = cmul(A2, A);
    const float2 A4 = cmul(A2, A2);

    // Act = A^SEG (closed form)
    const float magS = expf(re * dt * (float)SEG);
    const float angS = im * dt * (float)SEG;
    const float2 Act = make_float2(magS * cosf(angS), magS * sinf(angS));

    // C2 = 2 * B_proj * (A-1)/eig
    const float inv = 1.f / (re * re + im * im);
    const float2 num = make_float2(A.x - 1.f, A.y);
    const float bp = B_proj[k];
    const float2 C2v = make_float2(2.f * bp * (num.x * re + num.y * im) * inv,
                                   2.f * bp * (num.y * re - num.x * im) * inv);

    const int t0 = w * SEG;
    const float* hp = h + ((size_t)b * T_LEN + t0) * D_DIM + d;

    // ---- phase A: segment carry S = sum_{j<SEG} A^{SEG-1-j} h[t0+j] ----
    // Four independent A^4 chains:
    //   S = A^3 c0 + A^2 c1 + A c2 + c3, c_i = sum_m (A^4)^{SEG/4-1-m} h_{4m+i}
    float2 c0 = {0.f, 0.f}, c1 = {0.f, 0.f}, c2 = {0.f, 0.f}, c3 = {0.f, 0.f};
    #pragma unroll 8
    for (int m = 0; m < SEG / 4; ++m) {
        float h0 = hp[(size_t)(4 * m + 0) * D_DIM];   // 256B/wave coalesced
        float h1 = hp[(size_t)(4 * m + 1) * D_DIM];
        float h2 = hp[(size_t)(4 * m + 2) * D_DIM];
        float h3 = hp[(size_t)(4 * m + 3) * D_DIM];
        c0 = cmul(A4, c0); c0.x += h0;
        c1 = cmul(A4, c1); c1.x += h1;
        c2 = cmul(A4, c2); c2.x += h2;
        c3 = cmul(A4, c3); c3.x += h3;
    }
    const float2 S = cadd(cadd(cmul(A3, c0), cmul(A2, c1)),
                          cadd(cmul(A, c2), c3));

    // ---- phase B: LDS scan across the 16 waves ----
    __shared__ float2 sm[NW][D_DIM];
    sm[w][d] = S;
    __syncthreads();

    float2 sv[NW - 1];
    #pragma unroll
    for (int v = 0; v < NW - 1; ++v)    // wave-uniform guard, static index
        sv[v] = (v < w) ? sm[v][d] : make_float2(0.f, 0.f);
    float2 x = {0.f, 0.f};              // x = sum_{v<w} Act^{w-1-v} S_v
    #pragma unroll
    for (int v = 0; v < NW - 1; ++v)
        if (v < w) x = cadd(cmul(Act, x), sv[v]);

    // ---- phase C: replay segment (h L2-hot), coalesced 256B/wave stores ----
    float* op = out + (((size_t)b * T_LEN + t0) * K_CH + k) * D_DIM + d;
    #pragma unroll 8
    for (int t = 0; t < SEG; ++t) {
        float hv = hp[(size_t)t * D_DIM];
        x = cmul(A, x);
        x.x += hv;
        op[(size_t)t * (K_CH * D_DIM)] = C2v.x * x.x - C2v.y * x.y;
    }
}

extern "C" void kernel_launch(void* const* d_in, const int* in_sizes, int n_in,
                              void* d_out, int out_size, void* d_ws, size_t ws_size,
                              hipStream_t stream) {
    const float* h          = (const float*)d_in[0];
    const float* log_neg_re = (const float*)d_in[1];
    const float* imag       = (const float*)d_in[2];
    const float* B_proj     = (const float*)d_in[3];
    const float* log_dt     = (const float*)d_in[4];
    float* out = (float*)d_out;

    // One kernel, one graph node. Grid 64 = (k,b); block 1024 = 16w x 64d.
    hipLaunchKernelGGL(s4d_block, dim3(B_SZ * K_CH), dim3(1024), 0, stream,
                       h, log_neg_re, imag, B_proj, log_dt, out);
}

// Round 15
// 16.134 us; speedup vs baseline: 1.7096x; 1.7096x over previous
//
#include <hip/hip_runtime.h>
#include <hip/hip_bf16.h>

// Problem constants (from reference)
#define T_LEN 2048
#define D_DIM 64
#define K_CH  8
#define B_SZ  8

// Single kernel, zero cross-block deps, full chip:
// 256 blocks = (b, k, dq) with dq = d-quarter (16 d's per block).
// Block = 1024 threads = 16 waves; wave w owns t-segment [w*128,(w+1)*128);
// lane = (s, d16): s = 32-step sub-segment, d16 = d within quarter.
#define SEG 128
#define SUB 32
#define NW (T_LEN / SEG)       // 16 waves

__device__ __forceinline__ float2 cmul(float2 a, float2 b) {
    return make_float2(a.x * b.x - a.y * b.y, a.x * b.y + a.y * b.x);
}
__device__ __forceinline__ float2 cadd(float2 a, float2 b) {
    return make_float2(a.x + b.x, a.y + b.y);
}
__device__ __forceinline__ float2 shfl2(float2 v, int lane) {
    return make_float2(__shfl(v.x, lane, 64), __shfl(v.y, lane, 64));
}

__global__ __launch_bounds__(1024) void s4d_one(
    const float* __restrict__ h,
    const float* __restrict__ log_neg_re,
    const float* __restrict__ imag,
    const float* __restrict__ B_proj,
    const float* __restrict__ log_dt,
    float* __restrict__ out)
{
    const int bid = blockIdx.x;          // 256 = dq(4) x k(8) x b(8)
    const int b  = bid & 7;              // bid%8=b -> sequence b on one XCD
    const int k  = (bid >> 3) & 7;
    const int dq = bid >> 6;             // 0..3
    const int w    = threadIdx.x >> 6;   // wave = t-segment
    const int lane = threadIdx.x & 63;
    const int s    = lane >> 4;          // 0..3: 32-step sub-segment
    const int d16  = lane & 15;
    const int d    = dq * 16 + d16;

    // ---- 1. issue all 32 h loads first (one exposed round trip) ----
    const int t0 = w * SEG + s * SUB;
    const float* hp = h + ((size_t)b * T_LEN + t0) * D_DIM + d;
    float hv[SUB];
    #pragma unroll
    for (int j = 0; j < SUB; ++j) hv[j] = hp[(size_t)j * D_DIM];

    // ---- 2. per-k constants (loads in flight) ----
    const float dt = expf(log_dt[0]);
    const float re = -expf(log_neg_re[k]);
    const float im = imag[k];
    const float mag = expf(re * dt);
    const float2 A  = make_float2(mag * cosf(im * dt), mag * sinf(im * dt));
    const float2 A2 = cmul(A, A);

    const float mag32 = expf(re * dt * 32.f);
    const float ang32 = im * dt * 32.f;
    const float2 a32  = make_float2(mag32 * cosf(ang32), mag32 * sinf(ang32));
    const float2 a64  = cmul(a32, a32);
    const float2 a96  = cmul(a64, a32);
    const float2 a128 = cmul(a64, a64);   // = A^SEG

    // C2 = 2 * B_proj * (A-1)/eig
    const float inv = 1.f / (re * re + im * im);
    const float2 num = make_float2(A.x - 1.f, A.y);
    const float bp = B_proj[k];
    const float2 C2v = make_float2(2.f * bp * (num.x * re + num.y * im) * inv,
                                   2.f * bp * (num.y * re - num.x * im) * inv);

    // ---- 3. phase A: 32-step sub-carry C = sum_j A^{31-j} hv[j] ----
    float2 ce = {0.f, 0.f}, co = {0.f, 0.f};
    #pragma unroll
    for (int m = 0; m < SUB / 2; ++m) {
        ce = cmul(A2, ce); ce.x += hv[2 * m];
        co = cmul(A2, co); co.x += hv[2 * m + 1];
    }
    const float2 C = cadd(cmul(A, ce), co);

    // ---- 4. wave-level: gather the 4 sub-carries for this (w,d16) ----
    const float2 c0 = shfl2(C, d16);
    const float2 c1 = shfl2(C, 16 + d16);
    const float2 c2 = shfl2(C, 32 + d16);
    const float2 c3 = shfl2(C, 48 + d16);
    // full 128-step segment carry: S = A^96 c0 + A^64 c1 + A^32 c2 + c3
    const float2 S = cadd(cadd(cmul(a96, c0), cmul(a64, c1)),
                          cadd(cmul(a32, c2), c3));

    // ---- 5. LDS scan across 16 waves: X_w = sum_{v<w} a128^{w-1-v} S_v ----
    __shared__ float2 sm[NW][16];
    if (s == 0) sm[w][d16] = S;
    __syncthreads();

    float2 sv[NW - 1];
    #pragma unroll
    for (int v = 0; v < NW - 1; ++v)    // wave-uniform guard, static index
        sv[v] = (v < w) ? sm[v][d16] : make_float2(0.f, 0.f);
    float2 x = {0.f, 0.f};
    #pragma unroll
    for (int v = 0; v < NW - 1; ++v)
        if (v < w) x = cadd(cmul(a128, x), sv[v]);

    // ---- 6. advance to this lane's sub-segment start ----
    if (s > 0) x = cadd(cmul(a32, x), c0);
    if (s > 1) x = cadd(cmul(a32, x), c1);
    if (s > 2) x = cadd(cmul(a32, x), c2);

    // ---- 7. replay 32 steps from registers, store ----
    float* op = out + (((size_t)b * T_LEN + t0) * K_CH + k) * D_DIM + d;
    #pragma unroll
    for (int j = 0; j < SUB; ++j) {
        x = cmul(A, x);
        x.x += hv[j];
        op[(size_t)j * (K_CH * D_DIM)] = C2v.x * x.x - C2v.y * x.y;  // 64B/16-lane sector
    }
}

extern "C" void kernel_launch(void* const* d_in, const int* in_sizes, int n_in,
                              void* d_out, int out_size, void* d_ws, size_t ws_size,
                              hipStream_t stream) {
    const float* h          = (const float*)d_in[0];
    const float* log_neg_re = (const float*)d_in[1];
    const float* imag       = (const float*)d_in[2];
    const float* B_proj     = (const float*)d_in[3];
    const float* log_dt     = (const float*)d_in[4];
    float* out = (float*)d_out;

    // One kernel, one graph node, 256 blocks (1/CU), 1024 threads.
    hipLaunchKernelGGL(s4d_one, dim3(256), dim3(1024), 0, stream,
                       h, log_neg_re, imag, B_proj, log_dt, out);
}